// Round 2
// baseline (46296.362 us; speedup 1.0000x reference)
//
#include <hip/hip_runtime.h>
#include <hip/hip_bf16.h>

// EncoderBiLSTMMaxPool — round 7: chain-batched MFMA recurrence.
// k_recur: 2 WGs (one per direction), 1024 threads = 16 waves. The 4 independent chains of a
// direction ride the MFMA M-rows (A row r = h of chain r&3), so Whh is read ONCE per step per
// direction instead of 4x, and it is FULLY register-resident: wave w owns units [16w,16w+16)
// for all 4 gate types = 4 N-tiles x 8 kf = 32 frags = 128 VGPRs. Zero LDS weight streaming
// (round 6's 128 KB/step LDS stream was the regression). D-layout: acc reg r = chain r, so
// lane (quad=chain, col=unit) finalizes 1 unit x 1 chain — no redundancy, no exchange, one
// barrier/step. xp (bias folded at GEMM epilogue) prefetched 2 steps ahead.

typedef _Float16 f16;
typedef _Float16 f16x8 __attribute__((ext_vector_type(8)));
typedef float    f32x4 __attribute__((ext_vector_type(4)));

#define B_  128
#define S_  128
#define H_  512
#define HH_ 256
#define M_  (B_ * S_)   // 16384
#define NG  1024        // gates per direction (4*HH)
#define K0  512         // LSTM input dim

__device__ __forceinline__ float sigmoidf_(float x) { return 1.0f / (1.0f + __expf(-x)); }
__device__ __forceinline__ float tanhf_(float x)    { return 1.0f - 2.0f / (__expf(2.0f * x) + 1.0f); }

__device__ __forceinline__ float ldf(const void* p, long i, int isbf) {
    return isbf ? __bfloat162float(((const __hip_bfloat16*)p)[i]) : ((const float*)p)[i];
}

__device__ __forceinline__ float sel4(f32x4 a, int q) {
    float v = a[0];
    if (q == 1) v = a[1];
    if (q == 2) v = a[2];
    if (q == 3) v = a[3];
    return v;
}

// ---------------- dtype detection (bf16 vs fp32 input buffers) ----------------
__global__ void k_detect(const unsigned short* __restrict__ e, int* __restrict__ flag) {
    __shared__ int cnt;
    if (threadIdx.x == 0) cnt = 0;
    __syncthreads();
    unsigned short v = e[threadIdx.x];
    int ex = (v >> 7) & 0xFF;
    if (ex >= 100 && ex < 127) atomicAdd(&cnt, 1);
    __syncthreads();
    if (threadIdx.x == 0) *flag = (cnt >= 200) ? 1 : 0;   // 1 = bf16, 0 = fp32
}

// ---------------- embedding ----------------
__global__ void k_embed(const int* __restrict__ rt, const int* __restrict__ re, const int* __restrict__ rm,
                        const void* __restrict__ Ert, const void* __restrict__ Ere,
                        const void* __restrict__ Erm, f16* __restrict__ emb,
                        const int* __restrict__ flag) {
    const int isbf = *flag;
    int gid = blockIdx.x * 256 + threadIdx.x;      // < 16384*512
    int bs = gid >> 9, h = gid & 511;
    float v = ldf(Ert, (long)rt[bs] * H_ + h, isbf)
            + ldf(Ere, (long)re[bs] * H_ + h, isbf)
            + ldf(Erm, (long)rm[bs] * H_ + h, isbf);
    emb[gid] = (f16)v;
}

// ---------------- weight conversion ----------------
// wih: f16 rows for k_gemm (layout [2][2][1024][512]).
// whhF: MFMA B-fragment image [ld=4][gt=64][kf=8][lane=64][8] f16:
//   lane holds W[gate = gt*16 + (lane&15)][k = kf*32 + (lane>>4)*8 + j], j=0..7.
// bias: bih+bhh f32 [4][1024] — folded into xp at the GEMM epilogue.
__global__ void k_wconv(const void* __restrict__ Wih, const void* __restrict__ Whh,
                        const void* __restrict__ bih, const void* __restrict__ bhh,
                        f16* __restrict__ wih, f16* __restrict__ whhF, float* __restrict__ bias,
                        const int* __restrict__ flag) {
    const int isbf = *flag;
    int gid = blockIdx.x * 256 + threadIdx.x;      // < 2,097,152
    wih[gid] = (f16)ldf(Wih, gid, isbf);
    if (gid < 1048576) {
        int j  = gid & 7;
        int ln = (gid >> 3) & 63;
        int kf = (gid >> 9) & 7;
        int gt = (gid >> 12) & 63;
        int ld = gid >> 18;
        int gate = gt * 16 + (ln & 15);
        int k    = kf * 32 + (ln >> 4) * 8 + j;
        whhF[gid] = (f16)ldf(Whh, ((long)ld * 1024 + gate) * 256 + k, isbf);
    }
    if (gid < 4096) bias[gid] = ldf(bih, gid, isbf) + ldf(bhh, gid, isbf);
}

// ---------------- GEMM: C[16384][2048] = A[16384][512] * W[2048][512]^T + bias (f16, fp32 acc) ----------------
__global__ __launch_bounds__(256) void k_gemm(const f16* __restrict__ A, const f16* __restrict__ Bm,
                                              f16* __restrict__ C, const float* __restrict__ bias) {
    const int bm = blockIdx.x & 127;
    const int bn = blockIdx.x >> 7;
    const int tid = threadIdx.x;
    const int lane = tid & 63, wave = tid >> 6;
    const int wm = wave & 1, wn = wave >> 1;
    __shared__ __align__(16) f16 As[128][72];
    __shared__ __align__(16) f16 Bs[128][72];
    f32x4 acc[4][4];
#pragma unroll
    for (int i = 0; i < 4; ++i)
#pragma unroll
        for (int jj = 0; jj < 4; ++jj) acc[i][jj] = (f32x4){0.f, 0.f, 0.f, 0.f};
    const long abase = (long)bm * 128 * K0;
    const long bbase = (long)bn * 128 * K0;
    for (int kt = 0; kt < K0; kt += 64) {
#pragma unroll
        for (int p = 0; p < 4; ++p) {
            int r = p * 32 + (tid >> 3), s = tid & 7;
            *(int4*)&As[r][s * 8] = *(const int4*)(A  + abase + (long)r * K0 + kt + s * 8);
            *(int4*)&Bs[r][s * 8] = *(const int4*)(Bm + bbase + (long)r * K0 + kt + s * 8);
        }
        __syncthreads();
        const int quad = lane >> 4, l15 = lane & 15;
#pragma unroll
        for (int kc = 0; kc < 64; kc += 32) {
            f16x8 af[4], bf[4];
#pragma unroll
            for (int mt = 0; mt < 4; ++mt) af[mt] = *(const f16x8*)&As[wm * 64 + mt * 16 + l15][kc + quad * 8];
#pragma unroll
            for (int nt = 0; nt < 4; ++nt) bf[nt] = *(const f16x8*)&Bs[wn * 64 + nt * 16 + l15][kc + quad * 8];
#pragma unroll
            for (int mt = 0; mt < 4; ++mt)
#pragma unroll
                for (int nt = 0; nt < 4; ++nt)
                    acc[mt][nt] = __builtin_amdgcn_mfma_f32_16x16x32_f16(af[mt], bf[nt], acc[mt][nt], 0, 0, 0);
        }
        __syncthreads();
    }
    const int quad = lane >> 4, l15 = lane & 15;
#pragma unroll
    for (int mt = 0; mt < 4; ++mt)
#pragma unroll
        for (int nt = 0; nt < 4; ++nt) {
            int col = bn * 128 + wn * 64 + nt * 16 + l15;
            float bv = bias[col];
#pragma unroll
            for (int r = 0; r < 4; ++r) {
                int row = bm * 128 + wm * 64 + mt * 16 + quad * 4 + r;
                C[(long)row * 2048 + col] = (f16)(acc[mt][nt][r] + bv);
            }
        }
}

// ---------------- recurrence: chain-batched persistent-weight MFMA ----------------
// grid = 2 (d = blockIdx.x), 1024 threads = 16 waves. Wave w owns units [16w,16w+16).
// wreg[tt][kf] = B-frag of N-tile (tt*16+w), all in VGPRs. A row r = h[chain r&3] (chains
// replicated into rows 4..15, results discarded). acc reg r = chain r; lane quad = its chain.
__global__ __launch_bounds__(1024, 1) void k_recur(
    const f16* __restrict__ xp,     // [16384][2048] input projections (bias included)
    const f16* __restrict__ whhF,   // [4][64][8][64][8] f16 fragment image
    const void* __restrict__ h0, const void* __restrict__ c0,
    f16* __restrict__ yf16,         // layer0 out [16384][512]
    void* __restrict__ yout,        // layer1 out (d_out bilstm region)
    int layer, const int* __restrict__ flag) {
    const int isbf = *flag;
    const int d = blockIdx.x;
    const int tid = threadIdx.x;
    const int w = tid >> 6, l = tid & 63;
    const int col = l & 15, quad = l >> 4;
    const int chain = quad;                         // lane's chain for state/activation
    const int u = 16 * w + col;                     // lane's unit
    const int ld = layer * 2 + d;
    const int xlane = d * NG + u;                   // + tt*256 selects gate type

    __shared__ __align__(16) f16 hbuf[2][4][272];   // [buf][chain][k], pad 272 -> 2-way banks

    // ---- stage weights: 32 register-resident fragments per wave (128 VGPRs) ----
    f16x8 wreg[4][8];
    {
        const f16* wb = whhF + (long)ld * (64 * 8 * 64 * 8);
#pragma unroll
        for (int tt = 0; tt < 4; ++tt)
#pragma unroll
            for (int kf = 0; kf < 8; ++kf) {
                const int gt = tt * 16 + w;
                wreg[tt][kf] = *(const f16x8*)(wb + (((long)gt * 8 + kf) * 64 + l) * 8);
            }
    }

    // ---- init state: chain 0 from h0/c0, chains 1..3 from reset ----
    float cst = (chain == 0) ? ldf(c0, ld * 256 + u, isbf) : 0.f;
    hbuf[0][chain][u] = (f16)((chain == 0) ? ldf(h0, ld * 256 + u, isbf) : 0.f);
    __syncthreads();

    // ---- prefetch xp for steps 0 and 1 (2-deep to cover HBM latency) ----
    f16 pxA[4], pxB[4];
    {
        const int b0 = chain * 32;
        const int t0 = d ? 127 : 0;
        const int t1 = d ? 126 : 1;
        const f16* xr0 = xp + ((long)b0 * 128 + t0) * 2048 + xlane;
        const f16* xr1 = xp + ((long)b0 * 128 + t1) * 2048 + xlane;
#pragma unroll
        for (int tt = 0; tt < 4; ++tt) { pxA[tt] = xr0[tt * 256]; pxB[tt] = xr1[tt * 256]; }
    }

#define RSTEP(S, RB, PXC)                                                                 \
    do {                                                                                  \
        float pv0 = (float)PXC[0], pv1 = (float)PXC[1], pv2 = (float)PXC[2],              \
              pv3 = (float)PXC[3];                                                        \
        { /* issue prefetch for step S+2 into PXC (consumed 2 steps later) */             \
            int sp = (S) + 2; if (sp > 4095) sp = 4095;                                   \
            int bb = chain * 32 + (sp >> 7), tii = sp & 127;                              \
            int tp = d ? (127 - tii) : tii;                                               \
            const f16* xr = xp + ((long)bb * 128 + tp) * 2048 + xlane;                    \
            PXC[0] = xr[0]; PXC[1] = xr[256]; PXC[2] = xr[512]; PXC[3] = xr[768];         \
        }                                                                                 \
        f32x4 acc[4];                                                                     \
        _Pragma("unroll")                                                                 \
        for (int tt = 0; tt < 4; ++tt) acc[tt] = (f32x4){0.f, 0.f, 0.f, 0.f};             \
        _Pragma("unroll")                                                                 \
        for (int kf = 0; kf < 8; ++kf) {                                                  \
            f16x8 ha = *(const f16x8*)&hbuf[RB][col & 3][kf * 32 + quad * 8];             \
            _Pragma("unroll")                                                             \
            for (int tt = 0; tt < 4; ++tt)                                                \
                acc[tt] = __builtin_amdgcn_mfma_f32_16x16x32_f16(ha, wreg[tt][kf],        \
                                                                 acc[tt], 0, 0, 0);       \
        }                                                                                 \
        float ig = sigmoidf_(sel4(acc[0], quad) + pv0);                                   \
        float fg = sigmoidf_(sel4(acc[1], quad) + pv1);                                   \
        float gg = tanhf_(sel4(acc[2], quad) + pv2);                                      \
        float og = sigmoidf_(sel4(acc[3], quad) + pv3);                                   \
        cst = fg * cst + ig * gg;                                                         \
        float hn = og * tanhf_(cst);                                                      \
        hbuf[(RB) ^ 1][chain][u] = (f16)hn;                                               \
        {                                                                                 \
            int bb = chain * 32 + ((S) >> 7), tii = (S) & 127;                            \
            int tc = d ? (127 - tii) : tii;                                               \
            long oidx = ((long)bb * 128 + tc) * 512 + d * 256 + u;                        \
            if (layer == 0) {                                                             \
                yf16[oidx] = (f16)hn;                                                     \
            } else {                                                                      \
                if (isbf) ((__hip_bfloat16*)yout)[oidx] = __float2bfloat16(hn);           \
                else      ((float*)yout)[oidx] = hn;                                      \
            }                                                                             \
        }                                                                                 \
        __syncthreads();                                                                  \
    } while (0)

    for (int it = 0; it < 2048; ++it) {
        const int s0 = it * 2;
        RSTEP(s0,     0, pxA);
        RSTEP(s0 + 1, 1, pxB);
    }
#undef RSTEP
}

// ---------------- max over batch axis ----------------
__global__ void k_maxpool(const void* __restrict__ bil, void* __restrict__ outbase,
                          const int* __restrict__ flag) {
    const int isbf = *flag;
    int gid = blockIdx.x * 256 + threadIdx.x;      // s*512+h, < 65536
    float m = -1e30f;
    for (int b = 0; b < 128; ++b)
        m = fmaxf(m, ldf(bil, (long)b * 65536 + gid, isbf));
    long o = (long)M_ * H_ + gid;
    if (isbf) ((__hip_bfloat16*)outbase)[o] = __float2bfloat16(m);
    else      ((float*)outbase)[o] = m;
}

extern "C" void kernel_launch(void* const* d_in, const int* in_sizes, int n_in,
                              void* d_out, int out_size, void* d_ws, size_t ws_size,
                              hipStream_t stream) {
    const int* rt = (const int*)d_in[0];
    const int* re = (const int*)d_in[1];
    const int* rm = (const int*)d_in[2];
    const void* h0  = d_in[3];
    const void* c0  = d_in[4];
    const void* Ert = d_in[5];
    const void* Ere = d_in[6];
    const void* Erm = d_in[7];
    const void* Wih = d_in[8];
    const void* Whh = d_in[9];
    const void* bih = d_in[10];
    const void* bhh = d_in[11];

    if (ws_size < 106971200u) return;

    char* ws = (char*)d_ws;
    f16*   emb  = (f16*)(ws);                      // 16,777,216 B
    f16*   wih  = (f16*)(ws + 16777216);           //  4,194,304 B  [2][2][1024][512]
    f16*   whhF = (f16*)(ws + 20971520);           //  2,097,152 B  [4][64][8][64][8] fragment image
    float* bias = (float*)(ws + 23068672);         //     16,384 B  [2][2][1024]
    f16*   xpb  = (f16*)(ws + 23085056);           // 67,108,864 B  [16384][2048]
    f16*   y0   = (f16*)(ws + 90193920);           // 16,777,216 B  [16384][512]
    int*   flag = (int*)(ws + 106971136);          //          4 B

    hipLaunchKernelGGL(k_detect, dim3(1),     dim3(256), 0, stream, (const unsigned short*)Ert, flag);
    hipLaunchKernelGGL(k_embed,  dim3(32768), dim3(256), 0, stream, rt, re, rm, Ert, Ere, Erm, emb, flag);
    hipLaunchKernelGGL(k_wconv,  dim3(8192),  dim3(256), 0, stream, Wih, Whh, bih, bhh, wih, whhF, bias, flag);
    hipLaunchKernelGGL(k_gemm,   dim3(2048),  dim3(256), 0, stream, emb, wih, xpb, bias);
    hipLaunchKernelGGL(k_recur,  dim3(2),     dim3(1024), 0, stream, xpb, whhF, h0, c0, y0, d_out, 0, flag);
    hipLaunchKernelGGL(k_gemm,   dim3(2048),  dim3(256), 0, stream, y0, wih + (long)2 * NG * K0, xpb, bias + 2048);
    hipLaunchKernelGGL(k_recur,  dim3(2),     dim3(1024), 0, stream, xpb, whhF, h0, c0, y0, d_out, 1, flag);
    hipLaunchKernelGGL(k_maxpool,dim3(256),   dim3(256), 0, stream, d_out, d_out, flag);
}

// Round 3
// 9044.643 us; speedup vs baseline: 5.1186x; 5.1186x over previous
//
#include <hip/hip_runtime.h>
#include <hip/hip_bf16.h>

// EncoderBiLSTMMaxPool — round 8: round-5 proven inner loop + cross-layer pipelining.
// One persistent kernel k_pipe (48 blocks x 512 thr, 1 block/CU via 134KB LDS):
//   blocks 0-7  : layer-0 recurrence (round-5 code), releases flag0[b] after each sample b.
//   blocks 8-39 : 32 GEMM workers; item = (sample b, half h2): wait flag0[b]==2, compute
//                 xp1 rows of b (128x1024 cols) IN-PLACE over dead xp0 rows, release flag1[b].
//   blocks 40-47: layer-1 recurrence, waits flag1[b]==2 before each sample b.
// Per-sample sync = 32 agent-scope atomics per WG (~µs total); pipeline exposure ~1 sample.
// Fallback to sequential round-5 path if workspace lacks the 1KB flag region.

typedef _Float16 f16;
typedef _Float16 h2_t  __attribute__((ext_vector_type(2)));
typedef _Float16 f16x8 __attribute__((ext_vector_type(8)));
typedef float    f32x4 __attribute__((ext_vector_type(4)));

#define B_  128
#define S_  128
#define H_  512
#define HH_ 256
#define M_  (B_ * S_)   // 16384
#define NG  1024        // gates per direction (4*HH)
#define K0  512         // LSTM input dim

#define WS_BASE 106971200u
#define WS_PIPE 106972224u   // + 256 ints of flags

__device__ __forceinline__ float sigmoidf_(float x) { return 1.0f / (1.0f + __expf(-x)); }
__device__ __forceinline__ float tanhf_(float x)    { return 1.0f - 2.0f / (__expf(2.0f * x) + 1.0f); }

__device__ __forceinline__ float ldf(const void* p, long i, int isbf) {
    return isbf ? __bfloat162float(((const __hip_bfloat16*)p)[i]) : ((const float*)p)[i];
}

__device__ __forceinline__ float dot2f(int w, int h, float acc) {
#if __has_builtin(__builtin_amdgcn_fdot2)
    return __builtin_amdgcn_fdot2(__builtin_bit_cast(h2_t, w), __builtin_bit_cast(h2_t, h), acc, false);
#else
    h2_t a = __builtin_bit_cast(h2_t, w), b = __builtin_bit_cast(h2_t, h);
    return acc + (float)a[0] * (float)b[0] + (float)a[1] * (float)b[1];
#endif
}

__device__ __forceinline__ void wait_ge(int* p, int v) {
    while (__hip_atomic_load(p, __ATOMIC_ACQUIRE, __HIP_MEMORY_SCOPE_AGENT) < v)
        __builtin_amdgcn_s_sleep(16);
}
__device__ __forceinline__ void release_add(int* p) {
    __hip_atomic_fetch_add(p, 1, __ATOMIC_RELEASE, __HIP_MEMORY_SCOPE_AGENT);
}

// ---------------- dtype detection (bf16 vs fp32 input buffers) ----------------
__global__ void k_detect(const unsigned short* __restrict__ e, int* __restrict__ flag) {
    __shared__ int cnt;
    if (threadIdx.x == 0) cnt = 0;
    __syncthreads();
    unsigned short v = e[threadIdx.x];
    int ex = (v >> 7) & 0xFF;
    if (ex >= 100 && ex < 127) atomicAdd(&cnt, 1);
    __syncthreads();
    if (threadIdx.x == 0) *flag = (cnt >= 200) ? 1 : 0;   // 1 = bf16, 0 = fp32
}

// ---------------- flag zero (must precede k_pipe on the stream, every replay) ----------------
__global__ void k_zero(int* __restrict__ flags) { flags[threadIdx.x] = 0; }

// ---------------- embedding ----------------
__global__ void k_embed(const int* __restrict__ rt, const int* __restrict__ re, const int* __restrict__ rm,
                        const void* __restrict__ Ert, const void* __restrict__ Ere,
                        const void* __restrict__ Erm, f16* __restrict__ emb,
                        const int* __restrict__ flag) {
    const int isbf = *flag;
    int gid = blockIdx.x * 256 + threadIdx.x;      // < 16384*512
    int bs = gid >> 9, h = gid & 511;
    float v = ldf(Ert, (long)rt[bs] * H_ + h, isbf)
            + ldf(Ere, (long)re[bs] * H_ + h, isbf)
            + ldf(Erm, (long)rm[bs] * H_ + h, isbf);
    emb[gid] = (f16)v;
}

// ---------------- weight conversion -> f16, bias = bih+bhh (f32) ----------------
__global__ void k_wconv(const void* __restrict__ Wih, const void* __restrict__ Whh,
                        const void* __restrict__ bih, const void* __restrict__ bhh,
                        f16* __restrict__ wih, f16* __restrict__ whh, float* __restrict__ bias,
                        const int* __restrict__ flag) {
    const int isbf = *flag;
    int gid = blockIdx.x * 256 + threadIdx.x;      // < 2,097,152
    wih[gid] = (f16)ldf(Wih, gid, isbf);
    if (gid < 1048576) whh[gid] = (f16)ldf(Whh, gid, isbf);
    if (gid < 4096)    bias[gid] = ldf(bih, gid, isbf) + ldf(bhh, gid, isbf);
}

// ---------------- GEMM: C[16384][2048] = A[16384][512] * W[2048][512]^T (f16, fp32 acc) ----------------
__global__ __launch_bounds__(256) void k_gemm(const f16* __restrict__ A, const f16* __restrict__ Bm,
                                              f16* __restrict__ C) {
    const int bm = blockIdx.x & 127;
    const int bn = blockIdx.x >> 7;
    const int tid = threadIdx.x;
    const int lane = tid & 63, wave = tid >> 6;
    const int wm = wave & 1, wn = wave >> 1;
    __shared__ __align__(16) f16 As[128][72];
    __shared__ __align__(16) f16 Bs[128][72];
    f32x4 acc[4][4];
#pragma unroll
    for (int i = 0; i < 4; ++i)
#pragma unroll
        for (int jj = 0; jj < 4; ++jj) acc[i][jj] = (f32x4){0.f, 0.f, 0.f, 0.f};
    const long abase = (long)bm * 128 * K0;
    const long bbase = (long)bn * 128 * K0;
    for (int kt = 0; kt < K0; kt += 64) {
#pragma unroll
        for (int p = 0; p < 4; ++p) {
            int r = p * 32 + (tid >> 3), s = tid & 7;
            *(int4*)&As[r][s * 8] = *(const int4*)(A  + abase + (long)r * K0 + kt + s * 8);
            *(int4*)&Bs[r][s * 8] = *(const int4*)(Bm + bbase + (long)r * K0 + kt + s * 8);
        }
        __syncthreads();
        const int quad = lane >> 4, l15 = lane & 15;
#pragma unroll
        for (int kc = 0; kc < 64; kc += 32) {
            f16x8 af[4], bf[4];
#pragma unroll
            for (int mt = 0; mt < 4; ++mt) af[mt] = *(const f16x8*)&As[wm * 64 + mt * 16 + l15][kc + quad * 8];
#pragma unroll
            for (int nt = 0; nt < 4; ++nt) bf[nt] = *(const f16x8*)&Bs[wn * 64 + nt * 16 + l15][kc + quad * 8];
#pragma unroll
            for (int mt = 0; mt < 4; ++mt)
#pragma unroll
                for (int nt = 0; nt < 4; ++nt)
                    acc[mt][nt] = __builtin_amdgcn_mfma_f32_16x16x32_f16(af[mt], bf[nt], acc[mt][nt], 0, 0, 0);
        }
        __syncthreads();
    }
    const int quad = lane >> 4, l15 = lane & 15;
#pragma unroll
    for (int mt = 0; mt < 4; ++mt)
#pragma unroll
        for (int nt = 0; nt < 4; ++nt)
#pragma unroll
            for (int r = 0; r < 4; ++r) {
                int row = bm * 128 + wm * 64 + mt * 16 + quad * 4 + r;
                int col = bn * 128 + wn * 64 + nt * 16 + l15;
                C[(long)row * 2048 + col] = (f16)acc[mt][nt][r];
            }
}

// ---------------- round-5 recurrence body (proven 6.34ms), with optional per-sample sync ----------------
// thread (j = tid&255, half = tid>>8) owns gates G0=2*half, G1=2*half+1 of unit j.
// Per gate: k<192 in VGPRs (48 int4 = 192 VGPRs), k>=192 in LDS. half==0 finalizes c,h.
// rel != nullptr: release rel[b] after finishing sample b (layer 0).
// acq != nullptr: wait acq[b] >= 2 before starting sample b (layer 1).
__device__ void recur_body(char* smem,
    const f16* __restrict__ xp, const f16* __restrict__ whh, const float* __restrict__ bias,
    const void* __restrict__ h0, const void* __restrict__ c0,
    f16* __restrict__ yf16, void* __restrict__ yout,
    int layer, int isbf, int q, int d, int* rel, int* acq) {

    const int tid = threadIdx.x;
    const int j = tid & 255, half = tid >> 8;
    const int G0 = half * 2, G1 = G0 + 1;
    const int ld = layer * 2 + d;
    const f16* wrow0 = whh + (long)ld * NG * 256;

    f16*    hbufB = (f16*)smem;                     // [2][256]
    int4*   wlds4 = (int4*)(smem + 1024);           // [half][gg][chunk][unit] = [2][2][8][256]
    float2* plds  = (float2*)(smem + 1024 + 131072);// [256]

    // stage weights: 24 int4 chunks (k<192) per gate into regs, 8 chunks into LDS
    int4 w4[2][24];
    {
        const int4* r0 = (const int4*)(wrow0 + (long)(G0 * 256 + j) * 256);
        const int4* r1 = (const int4*)(wrow0 + (long)(G1 * 256 + j) * 256);
#pragma unroll
        for (int c = 0; c < 24; ++c) { w4[0][c] = r0[c]; w4[1][c] = r1[c]; }
#pragma unroll
        for (int c = 0; c < 8; ++c) {
            wlds4[((half * 2 + 0) * 8 + c) * 256 + j] = r0[24 + c];
            wlds4[((half * 2 + 1) * 8 + c) * 256 + j] = r1[24 + c];
        }
    }
    const float b0 = bias[ld * NG + G0 * 256 + j];
    const float b1 = bias[ld * NG + G1 * 256 + j];

    float cst = 0.f;
    if (half == 0) {
        float hv = 0.f;
        if (q == 0) {                               // chain 0 starts from h0/c0; others from reset
            cst = ldf(c0, ld * 256 + j, isbf);
            hv  = ldf(h0, ld * 256 + j, isbf);
        }
        hbufB[j] = (f16)hv;
    }
    __syncthreads();

    int cur = 0;
    for (int i = 0; i < 32; ++i) {
        const int b = q * 32 + i;
        if (acq) wait_ge(&acq[b], 2);               // layer-1: xp rows of sample b ready
        for (int ti = 0; ti < 128; ++ti) {
            const int t = d ? (127 - ti) : ti;
            const f16* xr = xp + ((long)b * 128 + t) * 2048 + d * NG + j;
            f16 px0h = xr[G0 * 256];                // loads hidden under the dot loop (vmcnt)
            f16 px1h = xr[G1 * 256];

            float a0 = b0, a1 = b1;
            const int4* hp = (const int4*)(hbufB + cur * 256);
            // k < 192: register weights, h staged in blocks of 4 chunks (bounded pressure)
#pragma unroll
            for (int blk = 0; blk < 6; ++blk) {
                int4 hh[4];
#pragma unroll
                for (int u = 0; u < 4; ++u) hh[u] = hp[blk * 4 + u];
#pragma unroll
                for (int u = 0; u < 4; ++u) {
                    int4 wa = w4[0][blk * 4 + u], wb = w4[1][blk * 4 + u];
                    a0 = dot2f(wa.x, hh[u].x, a0); a0 = dot2f(wa.y, hh[u].y, a0);
                    a0 = dot2f(wa.z, hh[u].z, a0); a0 = dot2f(wa.w, hh[u].w, a0);
                    a1 = dot2f(wb.x, hh[u].x, a1); a1 = dot2f(wb.y, hh[u].y, a1);
                    a1 = dot2f(wb.z, hh[u].z, a1); a1 = dot2f(wb.w, hh[u].w, a1);
                }
            }
            // k in [192,256): LDS weights (b128 stride-16, conflict-free)
#pragma unroll
            for (int c = 0; c < 8; ++c) {
                int4 hh = hp[24 + c];
                int4 wa = wlds4[((half * 2 + 0) * 8 + c) * 256 + j];
                int4 wb = wlds4[((half * 2 + 1) * 8 + c) * 256 + j];
                a0 = dot2f(wa.x, hh.x, a0); a0 = dot2f(wa.y, hh.y, a0);
                a0 = dot2f(wa.z, hh.z, a0); a0 = dot2f(wa.w, hh.w, a0);
                a1 = dot2f(wb.x, hh.x, a1); a1 = dot2f(wb.y, hh.y, a1);
                a1 = dot2f(wb.z, hh.z, a1); a1 = dot2f(wb.w, hh.w, a1);
            }
            a0 += (float)px0h;
            a1 += (float)px1h;

            if (half) plds[j] = make_float2(a0, a1);// g, o preacts (bias+xp included)
            __syncthreads();                        // B1: preacts exchanged
            if (!half) {
                float2 go = plds[j];
                float ig = sigmoidf_(a0);           // gate i
                float fg = sigmoidf_(a1);           // gate f
                float gg = tanhf_(go.x);            // gate g
                float og = sigmoidf_(go.y);         // gate o
                cst = fg * cst + ig * gg;
                float hn = og * tanhf_(cst);
                hbufB[(cur ^ 1) * 256 + j] = (f16)hn;
                long oidx = ((long)b * 128 + t) * 512 + d * 256 + j;
                if (layer == 0) {
                    yf16[oidx] = (f16)hn;
                } else {
                    if (isbf) ((__hip_bfloat16*)yout)[oidx] = __float2bfloat16(hn);
                    else      ((float*)yout)[oidx] = hn;
                }
            }
            cur ^= 1;
            __syncthreads();                        // B2: hbuf[cur] ready for all
        }
        if (rel) {                                  // layer-0: publish sample b
            __threadfence();                        // each thread drains its y0 stores (agent scope)
            __syncthreads();
            if (tid == 0) release_add(&rel[b]);
        }
    }
}

// ---------------- pipelined GEMM worker: xp1 for (sample b, half h2), in-place over xp0 ----------------
// 512 threads = 8 waves as 2(row-half) x 4(col-quarter) over a 128x256 tile; 4 slabs per item.
__device__ void worker_body(char* smem, const f16* __restrict__ y0, const f16* __restrict__ wih1,
                            f16* __restrict__ xpb, int* flags, int wid) {
    f16 (*As)[72] = (f16(*)[72])smem;               // 128x72 = 18,432 B
    f16 (*Bs)[72] = (f16(*)[72])(smem + 18432);     // 256x72 = 36,864 B
    const int tid = threadIdx.x;
    const int lane = tid & 63, wave = tid >> 6;
    const int wm = wave & 1, wn = wave >> 1;
    const int quad = lane >> 4, l15 = lane & 15;

    for (int m = wid; m < 256; m += 32) {           // completion order: i ascending
        const int i = m >> 3, q = (m >> 1) & 3, h2 = m & 1;
        const int b = q * 32 + i;
        wait_ge(&flags[b], 2);                      // both dirs of layer-0 done with sample b
        for (int slab = 0; slab < 4; ++slab) {
            const int n0 = h2 * 1024 + slab * 256;
            f32x4 acc[4][4];
#pragma unroll
            for (int a = 0; a < 4; ++a)
#pragma unroll
                for (int c = 0; c < 4; ++c) acc[a][c] = (f32x4){0.f, 0.f, 0.f, 0.f};
            for (int kt = 0; kt < 512; kt += 64) {
#pragma unroll
                for (int p = 0; p < 2; ++p) {
                    int r = p * 64 + (tid >> 3), s = tid & 7;
                    *(int4*)&As[r][s * 8] = *(const int4*)(y0 + ((long)(b * 128 + r)) * 512 + kt + s * 8);
                }
#pragma unroll
                for (int p = 0; p < 4; ++p) {
                    int r = p * 64 + (tid >> 3), s = tid & 7;
                    *(int4*)&Bs[r][s * 8] = *(const int4*)(wih1 + ((long)(n0 + r)) * 512 + kt + s * 8);
                }
                __syncthreads();
#pragma unroll
                for (int kc = 0; kc < 64; kc += 32) {
                    f16x8 af[4], bf[4];
#pragma unroll
                    for (int mt = 0; mt < 4; ++mt) af[mt] = *(const f16x8*)&As[wm * 64 + mt * 16 + l15][kc + quad * 8];
#pragma unroll
                    for (int nt = 0; nt < 4; ++nt) bf[nt] = *(const f16x8*)&Bs[wn * 64 + nt * 16 + l15][kc + quad * 8];
#pragma unroll
                    for (int mt = 0; mt < 4; ++mt)
#pragma unroll
                        for (int nt = 0; nt < 4; ++nt)
                            acc[mt][nt] = __builtin_amdgcn_mfma_f32_16x16x32_f16(af[mt], bf[nt], acc[mt][nt], 0, 0, 0);
                }
                __syncthreads();
            }
#pragma unroll
            for (int mt = 0; mt < 4; ++mt)
#pragma unroll
                for (int nt = 0; nt < 4; ++nt)
#pragma unroll
                    for (int r = 0; r < 4; ++r) {
                        int row = b * 128 + wm * 64 + mt * 16 + quad * 4 + r;
                        int col = n0 + wn * 64 + nt * 16 + l15;
                        xpb[(long)row * 2048 + col] = (f16)acc[mt][nt][r];
                    }
        }
        __threadfence();
        __syncthreads();
        if (tid == 0) release_add(&flags[128 + b]); // half done -> flag1[b] += 1 (target 2)
    }
}

// ---------------- fused pipeline kernel ----------------
__global__ __launch_bounds__(512, 1) void k_pipe(
    f16* __restrict__ xpb, const f16* __restrict__ whh, const float* __restrict__ bias,
    const void* __restrict__ h0, const void* __restrict__ c0,
    f16* __restrict__ y0, void* __restrict__ yout, const f16* __restrict__ wih1,
    int* __restrict__ flags, const int* __restrict__ flag) {
    __shared__ __align__(16) char smem[134144];
    const int blk = blockIdx.x;
    if (blk < 8) {
        recur_body(smem, xpb, whh, bias, h0, c0, y0, yout, 0, *flag, blk >> 1, blk & 1, flags, nullptr);
    } else if (blk < 40) {
        worker_body(smem, y0, wih1, xpb, flags, blk - 8);
    } else {
        const int r = blk - 40;
        recur_body(smem, xpb, whh, bias, h0, c0, y0, yout, 1, *flag, r >> 1, r & 1, nullptr, flags + 128);
    }
}

// ---------------- fallback: round-5 standalone recurrence ----------------
__global__ __launch_bounds__(512, 1) void k_recur_solo(
    const f16* __restrict__ xp, const f16* __restrict__ whh, const float* __restrict__ bias,
    const void* __restrict__ h0, const void* __restrict__ c0,
    f16* __restrict__ yf16, void* __restrict__ yout, int layer, const int* __restrict__ flag) {
    __shared__ __align__(16) char smem[134144];
    recur_body(smem, xp, whh, bias, h0, c0, yf16, yout, layer, *flag,
               blockIdx.x >> 1, blockIdx.x & 1, nullptr, nullptr);
}

// ---------------- max over batch axis ----------------
__global__ void k_maxpool(const void* __restrict__ bil, void* __restrict__ outbase,
                          const int* __restrict__ flag) {
    const int isbf = *flag;
    int gid = blockIdx.x * 256 + threadIdx.x;      // s*512+h, < 65536
    float m = -1e30f;
    for (int b = 0; b < 128; ++b)
        m = fmaxf(m, ldf(bil, (long)b * 65536 + gid, isbf));
    long o = (long)M_ * H_ + gid;
    if (isbf) ((__hip_bfloat16*)outbase)[o] = __float2bfloat16(m);
    else      ((float*)outbase)[o] = m;
}

extern "C" void kernel_launch(void* const* d_in, const int* in_sizes, int n_in,
                              void* d_out, int out_size, void* d_ws, size_t ws_size,
                              hipStream_t stream) {
    const int* rt = (const int*)d_in[0];
    const int* re = (const int*)d_in[1];
    const int* rm = (const int*)d_in[2];
    const void* h0  = d_in[3];
    const void* c0  = d_in[4];
    const void* Ert = d_in[5];
    const void* Ere = d_in[6];
    const void* Erm = d_in[7];
    const void* Wih = d_in[8];
    const void* Whh = d_in[9];
    const void* bih = d_in[10];
    const void* bhh = d_in[11];

    if (ws_size < WS_BASE) return;
    const bool pipe = (ws_size >= WS_PIPE);

    char* ws = (char*)d_ws;
    f16*   emb  = (f16*)(ws);                      // 16,777,216 B
    f16*   wih  = (f16*)(ws + 16777216);           //  4,194,304 B  [2][2][1024][512]
    f16*   whh  = (f16*)(ws + 20971520);           //  2,097,152 B  [2][2][1024][256]
    float* bias = (float*)(ws + 23068672);         //     16,384 B  [2][2][1024]
    f16*   xpb  = (f16*)(ws + 23085056);           // 67,108,864 B  [16384][2048]
    f16*   y0   = (f16*)(ws + 90193920);           // 16,777,216 B  [16384][512]
    int*   flag = (int*)(ws + 106971136);          //          4 B
    int*   flags= (int*)(ws + 106971200);          //      1,024 B  flag0[128] + flag1[128]

    hipLaunchKernelGGL(k_detect, dim3(1),     dim3(256), 0, stream, (const unsigned short*)Ert, flag);
    hipLaunchKernelGGL(k_embed,  dim3(32768), dim3(256), 0, stream, rt, re, rm, Ert, Ere, Erm, emb, flag);
    hipLaunchKernelGGL(k_wconv,  dim3(8192),  dim3(256), 0, stream, Wih, Whh, bih, bhh, wih, whh, bias, flag);
    hipLaunchKernelGGL(k_gemm,   dim3(2048),  dim3(256), 0, stream, emb, wih, xpb);
    if (pipe) {
        hipLaunchKernelGGL(k_zero, dim3(1),   dim3(256), 0, stream, flags);
        hipLaunchKernelGGL(k_pipe, dim3(48),  dim3(512), 0, stream,
                           xpb, whh, bias, h0, c0, y0, d_out, wih + (long)2 * NG * K0, flags, flag);
    } else {
        hipLaunchKernelGGL(k_recur_solo, dim3(8), dim3(512), 0, stream, xpb, whh, bias, h0, c0, y0, d_out, 0, flag);
        hipLaunchKernelGGL(k_gemm,  dim3(2048), dim3(256), 0, stream, y0, wih + (long)2 * NG * K0, xpb);
        hipLaunchKernelGGL(k_recur_solo, dim3(8), dim3(512), 0, stream, xpb, whh, bias, h0, c0, y0, d_out, 1, flag);
    }
    hipLaunchKernelGGL(k_maxpool, dim3(256),  dim3(256), 0, stream, d_out, d_out, flag);
}

// Round 5
// 8794.449 us; speedup vs baseline: 5.2643x; 1.0284x over previous
//
#include <hip/hip_runtime.h>
#include <hip/hip_bf16.h>

// EncoderBiLSTMMaxPool — round 10: round-9 with s_sleep operand as compile-time constant
// (template param — builtin requires a literal). Everything else identical to round 9:
//   (1) single-thread relaxed poll + one acquire + barrier (was 512-thread acquire storm)
//   (2) single-thread threadfence+release after barrier (was 512x buffer_wbl2)
//   (3) typed union LDS overlay (round-5 array types, no char+cast aliasing pessimization)

typedef _Float16 f16;
typedef _Float16 h2_t  __attribute__((ext_vector_type(2)));
typedef _Float16 f16x8 __attribute__((ext_vector_type(8)));
typedef float    f32x4 __attribute__((ext_vector_type(4)));

#define B_  128
#define S_  128
#define H_  512
#define HH_ 256
#define M_  (B_ * S_)   // 16384
#define NG  1024        // gates per direction (4*HH)
#define K0  512         // LSTM input dim

#define WS_BASE 106971200u
#define WS_PIPE 106972224u   // + 256 ints of flags

__device__ __forceinline__ float sigmoidf_(float x) { return 1.0f / (1.0f + __expf(-x)); }
__device__ __forceinline__ float tanhf_(float x)    { return 1.0f - 2.0f / (__expf(2.0f * x) + 1.0f); }

__device__ __forceinline__ float ldf(const void* p, long i, int isbf) {
    return isbf ? __bfloat162float(((const __hip_bfloat16*)p)[i]) : ((const float*)p)[i];
}

__device__ __forceinline__ float dot2f(int w, int h, float acc) {
#if __has_builtin(__builtin_amdgcn_fdot2)
    return __builtin_amdgcn_fdot2(__builtin_bit_cast(h2_t, w), __builtin_bit_cast(h2_t, h), acc, false);
#else
    h2_t a = __builtin_bit_cast(h2_t, w), b = __builtin_bit_cast(h2_t, h);
    return acc + (float)a[0] * (float)b[0] + (float)a[1] * (float)b[1];
#endif
}

// ---- sync helpers: single-thread poll / single-thread release (contention-free) ----
template <int SLP>
__device__ __forceinline__ void block_wait_ge(int* p, int v) {
    if (threadIdx.x == 0) {
        while (__hip_atomic_load(p, __ATOMIC_RELAXED, __HIP_MEMORY_SCOPE_AGENT) < v)
            __builtin_amdgcn_s_sleep(SLP);
        (void)__hip_atomic_load(p, __ATOMIC_ACQUIRE, __HIP_MEMORY_SCOPE_AGENT); // inv L1/L2 once
    }
    __syncthreads();
}
// call AFTER __syncthreads (vmcnt drained at barrier): one thread flushes L2 + releases
__device__ __forceinline__ void block_release(int* p) {
    if (threadIdx.x == 0) {
        __threadfence();                          // wb L2 (cross-XCD visibility of block's stores)
        __hip_atomic_fetch_add(p, 1, __ATOMIC_RELEASE, __HIP_MEMORY_SCOPE_AGENT);
    }
}

// ---- LDS overlay: recur (134,144 B) / worker (55,296 B) ----
struct SmemRecur {
    f16    hbuf[2][256];
    int4   wlds4[2][2][8][256];   // [half][gg][chunk][unit]
    float2 plds[256];
};
struct SmemWorker {
    f16 As[128][72];
    f16 Bs[256][72];
};
union PipeSmem { SmemRecur r; SmemWorker w; };

// ---------------- dtype detection (bf16 vs fp32 input buffers) ----------------
__global__ void k_detect(const unsigned short* __restrict__ e, int* __restrict__ flag) {
    __shared__ int cnt;
    if (threadIdx.x == 0) cnt = 0;
    __syncthreads();
    unsigned short v = e[threadIdx.x];
    int ex = (v >> 7) & 0xFF;
    if (ex >= 100 && ex < 127) atomicAdd(&cnt, 1);
    __syncthreads();
    if (threadIdx.x == 0) *flag = (cnt >= 200) ? 1 : 0;   // 1 = bf16, 0 = fp32
}

// ---------------- flag zero (precedes k_pipe on the stream, every replay) ----------------
__global__ void k_zero(int* __restrict__ flags) { flags[threadIdx.x] = 0; }

// ---------------- embedding ----------------
__global__ void k_embed(const int* __restrict__ rt, const int* __restrict__ re, const int* __restrict__ rm,
                        const void* __restrict__ Ert, const void* __restrict__ Ere,
                        const void* __restrict__ Erm, f16* __restrict__ emb,
                        const int* __restrict__ flag) {
    const int isbf = *flag;
    int gid = blockIdx.x * 256 + threadIdx.x;      // < 16384*512
    int bs = gid >> 9, h = gid & 511;
    float v = ldf(Ert, (long)rt[bs] * H_ + h, isbf)
            + ldf(Ere, (long)re[bs] * H_ + h, isbf)
            + ldf(Erm, (long)rm[bs] * H_ + h, isbf);
    emb[gid] = (f16)v;
}

// ---------------- weight conversion -> f16, bias = bih+bhh (f32) ----------------
__global__ void k_wconv(const void* __restrict__ Wih, const void* __restrict__ Whh,
                        const void* __restrict__ bih, const void* __restrict__ bhh,
                        f16* __restrict__ wih, f16* __restrict__ whh, float* __restrict__ bias,
                        const int* __restrict__ flag) {
    const int isbf = *flag;
    int gid = blockIdx.x * 256 + threadIdx.x;      // < 2,097,152
    wih[gid] = (f16)ldf(Wih, gid, isbf);
    if (gid < 1048576) whh[gid] = (f16)ldf(Whh, gid, isbf);
    if (gid < 4096)    bias[gid] = ldf(bih, gid, isbf) + ldf(bhh, gid, isbf);
}

// ---------------- GEMM: C[16384][2048] = A[16384][512] * W[2048][512]^T (f16, fp32 acc) ----------------
__global__ __launch_bounds__(256) void k_gemm(const f16* __restrict__ A, const f16* __restrict__ Bm,
                                              f16* __restrict__ C) {
    const int bm = blockIdx.x & 127;
    const int bn = blockIdx.x >> 7;
    const int tid = threadIdx.x;
    const int lane = tid & 63, wave = tid >> 6;
    const int wm = wave & 1, wn = wave >> 1;
    __shared__ __align__(16) f16 As[128][72];
    __shared__ __align__(16) f16 Bs[128][72];
    f32x4 acc[4][4];
#pragma unroll
    for (int i = 0; i < 4; ++i)
#pragma unroll
        for (int jj = 0; jj < 4; ++jj) acc[i][jj] = (f32x4){0.f, 0.f, 0.f, 0.f};
    const long abase = (long)bm * 128 * K0;
    const long bbase = (long)bn * 128 * K0;
    for (int kt = 0; kt < K0; kt += 64) {
#pragma unroll
        for (int p = 0; p < 4; ++p) {
            int r = p * 32 + (tid >> 3), s = tid & 7;
            *(int4*)&As[r][s * 8] = *(const int4*)(A  + abase + (long)r * K0 + kt + s * 8);
            *(int4*)&Bs[r][s * 8] = *(const int4*)(Bm + bbase + (long)r * K0 + kt + s * 8);
        }
        __syncthreads();
        const int quad = lane >> 4, l15 = lane & 15;
#pragma unroll
        for (int kc = 0; kc < 64; kc += 32) {
            f16x8 af[4], bf[4];
#pragma unroll
            for (int mt = 0; mt < 4; ++mt) af[mt] = *(const f16x8*)&As[wm * 64 + mt * 16 + l15][kc + quad * 8];
#pragma unroll
            for (int nt = 0; nt < 4; ++nt) bf[nt] = *(const f16x8*)&Bs[wn * 64 + nt * 16 + l15][kc + quad * 8];
#pragma unroll
            for (int mt = 0; mt < 4; ++mt)
#pragma unroll
                for (int nt = 0; nt < 4; ++nt)
                    acc[mt][nt] = __builtin_amdgcn_mfma_f32_16x16x32_f16(af[mt], bf[nt], acc[mt][nt], 0, 0, 0);
        }
        __syncthreads();
    }
    const int quad = lane >> 4, l15 = lane & 15;
#pragma unroll
    for (int mt = 0; mt < 4; ++mt)
#pragma unroll
        for (int nt = 0; nt < 4; ++nt)
#pragma unroll
            for (int r = 0; r < 4; ++r) {
                int row = bm * 128 + wm * 64 + mt * 16 + quad * 4 + r;
                int col = bn * 128 + wn * 64 + nt * 16 + l15;
                C[(long)row * 2048 + col] = (f16)acc[mt][nt][r];
            }
}

// ---------------- round-5 recurrence body, optional per-sample sync ----------------
// thread (j = tid&255, half = tid>>8) owns gates G0=2*half, G1=2*half+1 of unit j.
// Per gate: k<192 in VGPRs (48 int4 = 192 VGPRs), k>=192 in LDS. half==0 finalizes c,h.
__device__ void recur_body(PipeSmem* SM,
    const f16* __restrict__ xp, const f16* __restrict__ whh, const float* __restrict__ bias,
    const void* __restrict__ h0, const void* __restrict__ c0,
    f16* __restrict__ yf16, void* __restrict__ yout,
    int layer, int isbf, int q, int d, int* rel, int* acq) {

    const int tid = threadIdx.x;
    const int j = tid & 255, half = tid >> 8;
    const int G0 = half * 2, G1 = G0 + 1;
    const int ld = layer * 2 + d;
    const f16* wrow0 = whh + (long)ld * NG * 256;

    SmemRecur& S = SM->r;

    // stage weights: 24 int4 chunks (k<192) per gate into regs, 8 chunks into LDS
    int4 w4[2][24];
    {
        const int4* r0 = (const int4*)(wrow0 + (long)(G0 * 256 + j) * 256);
        const int4* r1 = (const int4*)(wrow0 + (long)(G1 * 256 + j) * 256);
#pragma unroll
        for (int c = 0; c < 24; ++c) { w4[0][c] = r0[c]; w4[1][c] = r1[c]; }
#pragma unroll
        for (int c = 0; c < 8; ++c) {
            S.wlds4[half][0][c][j] = r0[24 + c];
            S.wlds4[half][1][c][j] = r1[24 + c];
        }
    }
    const float b0 = bias[ld * NG + G0 * 256 + j];
    const float b1 = bias[ld * NG + G1 * 256 + j];

    float cst = 0.f;
    if (half == 0) {
        float hv = 0.f;
        if (q == 0) {                               // chain 0 starts from h0/c0; others from reset
            cst = ldf(c0, ld * 256 + j, isbf);
            hv  = ldf(h0, ld * 256 + j, isbf);
        }
        S.hbuf[0][j] = (f16)hv;
    }
    __syncthreads();

    int cur = 0;
    for (int i = 0; i < 32; ++i) {
        const int b = q * 32 + i;
        if (acq) block_wait_ge<2>(&acq[b], 2);      // layer-1: xp rows of sample b ready
        for (int ti = 0; ti < 128; ++ti) {
            const int t = d ? (127 - ti) : ti;
            const f16* xr = xp + ((long)b * 128 + t) * 2048 + d * NG + j;
            f16 px0h = xr[G0 * 256];                // loads hidden under the dot loop (vmcnt)
            f16 px1h = xr[G1 * 256];

            float a0 = b0, a1 = b1;
            const int4* hp = (const int4*)S.hbuf[cur];
            // k < 192: register weights, h staged in blocks of 4 chunks (bounded pressure)
#pragma unroll
            for (int blk = 0; blk < 6; ++blk) {
                int4 hh[4];
#pragma unroll
                for (int u = 0; u < 4; ++u) hh[u] = hp[blk * 4 + u];
#pragma unroll
                for (int u = 0; u < 4; ++u) {
                    int4 wa = w4[0][blk * 4 + u], wb = w4[1][blk * 4 + u];
                    a0 = dot2f(wa.x, hh[u].x, a0); a0 = dot2f(wa.y, hh[u].y, a0);
                    a0 = dot2f(wa.z, hh[u].z, a0); a0 = dot2f(wa.w, hh[u].w, a0);
                    a1 = dot2f(wb.x, hh[u].x, a1); a1 = dot2f(wb.y, hh[u].y, a1);
                    a1 = dot2f(wb.z, hh[u].z, a1); a1 = dot2f(wb.w, hh[u].w, a1);
                }
            }
            // k in [192,256): LDS weights (b128 stride-16, conflict-free)
#pragma unroll
            for (int c = 0; c < 8; ++c) {
                int4 hh = hp[24 + c];
                int4 wa = S.wlds4[half][0][c][j];
                int4 wb = S.wlds4[half][1][c][j];
                a0 = dot2f(wa.x, hh.x, a0); a0 = dot2f(wa.y, hh.y, a0);
                a0 = dot2f(wa.z, hh.z, a0); a0 = dot2f(wa.w, hh.w, a0);
                a1 = dot2f(wb.x, hh.x, a1); a1 = dot2f(wb.y, hh.y, a1);
                a1 = dot2f(wb.z, hh.z, a1); a1 = dot2f(wb.w, hh.w, a1);
            }
            a0 += (float)px0h;
            a1 += (float)px1h;

            if (half) S.plds[j] = make_float2(a0, a1);  // g, o preacts (bias+xp included)
            __syncthreads();                        // B1: preacts exchanged
            if (!half) {
                float2 go = S.plds[j];
                float ig = sigmoidf_(a0);           // gate i
                float fg = sigmoidf_(a1);           // gate f
                float gg = tanhf_(go.x);            // gate g
                float og = sigmoidf_(go.y);         // gate o
                cst = fg * cst + ig * gg;
                float hn = og * tanhf_(cst);
                S.hbuf[cur ^ 1][j] = (f16)hn;
                long oidx = ((long)b * 128 + t) * 512 + d * 256 + j;
                if (layer == 0) {
                    yf16[oidx] = (f16)hn;
                } else {
                    if (isbf) ((__hip_bfloat16*)yout)[oidx] = __float2bfloat16(hn);
                    else      ((float*)yout)[oidx] = hn;
                }
            }
            cur ^= 1;
            __syncthreads();                        // B2: hbuf[cur] ready for all (drains vmcnt)
        }
        if (rel) block_release(&rel[b]);            // layer-0: publish sample b (1 thread)
    }
}

// ---------------- pipelined GEMM worker: xp1 for (sample b, half h2), in-place over xp0 ----------------
// 512 threads = 8 waves as 2(row-half) x 4(col-quarter) over a 128x256 tile; 4 slabs per item.
__device__ void worker_body(PipeSmem* SM, const f16* __restrict__ y0, const f16* __restrict__ wih1,
                            f16* __restrict__ xpb, int* flags, int wid) {
    SmemWorker& S = SM->w;
    const int tid = threadIdx.x;
    const int lane = tid & 63, wave = tid >> 6;
    const int wm = wave & 1, wn = wave >> 1;
    const int quad = lane >> 4, l15 = lane & 15;

    for (int m = wid; m < 256; m += 32) {           // completion order: i ascending
        const int i = m >> 3, q = (m >> 1) & 3, h2 = m & 1;
        const int b = q * 32 + i;
        block_wait_ge<32>(&flags[b], 2);            // both dirs of layer-0 done with sample b
        for (int slab = 0; slab < 4; ++slab) {
            const int n0 = h2 * 1024 + slab * 256;
            f32x4 acc[4][4];
#pragma unroll
            for (int a = 0; a < 4; ++a)
#pragma unroll
                for (int c = 0; c < 4; ++c) acc[a][c] = (f32x4){0.f, 0.f, 0.f, 0.f};
            for (int kt = 0; kt < 512; kt += 64) {
#pragma unroll
                for (int p = 0; p < 2; ++p) {
                    int r = p * 64 + (tid >> 3), s = tid & 7;
                    *(int4*)&S.As[r][s * 8] = *(const int4*)(y0 + ((long)(b * 128 + r)) * 512 + kt + s * 8);
                }
#pragma unroll
                for (int p = 0; p < 4; ++p) {
                    int r = p * 64 + (tid >> 3), s = tid & 7;
                    *(int4*)&S.Bs[r][s * 8] = *(const int4*)(wih1 + ((long)(n0 + r)) * 512 + kt + s * 8);
                }
                __syncthreads();
#pragma unroll
                for (int kc = 0; kc < 64; kc += 32) {
                    f16x8 af[4], bf[4];
#pragma unroll
                    for (int mt = 0; mt < 4; ++mt) af[mt] = *(const f16x8*)&S.As[wm * 64 + mt * 16 + l15][kc + quad * 8];
#pragma unroll
                    for (int nt = 0; nt < 4; ++nt) bf[nt] = *(const f16x8*)&S.Bs[wn * 64 + nt * 16 + l15][kc + quad * 8];
#pragma unroll
                    for (int mt = 0; mt < 4; ++mt)
#pragma unroll
                        for (int nt = 0; nt < 4; ++nt)
                            acc[mt][nt] = __builtin_amdgcn_mfma_f32_16x16x32_f16(af[mt], bf[nt], acc[mt][nt], 0, 0, 0);
                }
                __syncthreads();
            }
#pragma unroll
            for (int mt = 0; mt < 4; ++mt)
#pragma unroll
                for (int nt = 0; nt < 4; ++nt)
#pragma unroll
                    for (int r = 0; r < 4; ++r) {
                        int row = b * 128 + wm * 64 + mt * 16 + quad * 4 + r;
                        int col = n0 + wn * 64 + nt * 16 + l15;
                        xpb[(long)row * 2048 + col] = (f16)acc[mt][nt][r];
                    }
        }
        __syncthreads();                            // all stores issued+drained (barrier waits vmcnt)
        block_release(&flags[128 + b]);             // half done -> flag1[b] += 1 (target 2)
    }
}

// ---------------- fused pipeline kernel ----------------
__global__ __launch_bounds__(512, 1) void k_pipe(
    f16* __restrict__ xpb, const f16* __restrict__ whh, const float* __restrict__ bias,
    const void* __restrict__ h0, const void* __restrict__ c0,
    f16* __restrict__ y0, void* __restrict__ yout, const f16* __restrict__ wih1,
    int* __restrict__ flags, const int* __restrict__ flag) {
    __shared__ __align__(16) PipeSmem SM;
    const int blk = blockIdx.x;
    if (blk < 8) {
        recur_body(&SM, xpb, whh, bias, h0, c0, y0, yout, 0, *flag, blk >> 1, blk & 1, flags, nullptr);
    } else if (blk < 40) {
        worker_body(&SM, y0, wih1, xpb, flags, blk - 8);
    } else {
        const int r = blk - 40;
        recur_body(&SM, xpb, whh, bias, h0, c0, y0, yout, 1, *flag, r >> 1, r & 1, nullptr, flags + 128);
    }
}

// ---------------- fallback: standalone recurrence ----------------
__global__ __launch_bounds__(512, 1) void k_recur_solo(
    const f16* __restrict__ xp, const f16* __restrict__ whh, const float* __restrict__ bias,
    const void* __restrict__ h0, const void* __restrict__ c0,
    f16* __restrict__ yf16, void* __restrict__ yout, int layer, const int* __restrict__ flag) {
    __shared__ __align__(16) PipeSmem SM;
    recur_body(&SM, xp, whh, bias, h0, c0, yf16, yout, layer, *flag,
               blockIdx.x >> 1, blockIdx.x & 1, nullptr, nullptr);
}

// ---------------- max over batch axis ----------------
__global__ void k_maxpool(const void* __restrict__ bil, void* __restrict__ outbase,
                          const int* __restrict__ flag) {
    const int isbf = *flag;
    int gid = blockIdx.x * 256 + threadIdx.x;      // s*512+h, < 65536
    float m = -1e30f;
    for (int b = 0; b < 128; ++b)
        m = fmaxf(m, ldf(bil, (long)b * 65536 + gid, isbf));
    long o = (long)M_ * H_ + gid;
    if (isbf) ((__hip_bfloat16*)outbase)[o] = __float2bfloat16(m);
    else      ((float*)outbase)[o] = m;
}

extern "C" void kernel_launch(void* const* d_in, const int* in_sizes, int n_in,
                              void* d_out, int out_size, void* d_ws, size_t ws_size,
                              hipStream_t stream) {
    const int* rt = (const int*)d_in[0];
    const int* re = (const int*)d_in[1];
    const int* rm = (const int*)d_in[2];
    const void* h0  = d_in[3];
    const void* c0  = d_in[4];
    const void* Ert = d_in[5];
    const void* Ere = d_in[6];
    const void* Erm = d_in[7];
    const void* Wih = d_in[8];
    const void* Whh = d_in[9];
    const void* bih = d_in[10];
    const void* bhh = d_in[11];

    if (ws_size < WS_BASE) return;
    const bool pipe = (ws_size >= WS_PIPE);

    char* ws = (char*)d_ws;
    f16*   emb  = (f16*)(ws);                      // 16,777,216 B
    f16*   wih  = (f16*)(ws + 16777216);           //  4,194,304 B  [2][2][1024][512]
    f16*   whh  = (f16*)(ws + 20971520);           //  2,097,152 B  [2][2][1024][256]
    float* bias = (float*)(ws + 23068672);         //     16,384 B  [2][2][1024]
    f16*   xpb  = (f16*)(ws + 23085056);           // 67,108,864 B  [16384][2048]
    f16*   y0   = (f16*)(ws + 90193920);           // 16,777,216 B  [16384][512]
    int*   flag = (int*)(ws + 106971136);          //          4 B
    int*   flags= (int*)(ws + 106971200);          //      1,024 B  flag0[128] + flag1[128]

    hipLaunchKernelGGL(k_detect, dim3(1),     dim3(256), 0, stream, (const unsigned short*)Ert, flag);
    hipLaunchKernelGGL(k_embed,  dim3(32768), dim3(256), 0, stream, rt, re, rm, Ert, Ere, Erm, emb, flag);
    hipLaunchKernelGGL(k_wconv,  dim3(8192),  dim3(256), 0, stream, Wih, Whh, bih, bhh, wih, whh, bias, flag);
    hipLaunchKernelGGL(k_gemm,   dim3(2048),  dim3(256), 0, stream, emb, wih, xpb);
    if (pipe) {
        hipLaunchKernelGGL(k_zero, dim3(1),   dim3(256), 0, stream, flags);
        hipLaunchKernelGGL(k_pipe, dim3(48),  dim3(512), 0, stream,
                           xpb, whh, bias, h0, c0, y0, d_out, wih + (long)2 * NG * K0, flags, flag);
    } else {
        hipLaunchKernelGGL(k_recur_solo, dim3(8), dim3(512), 0, stream, xpb, whh, bias, h0, c0, y0, d_out, 0, flag);
        hipLaunchKernelGGL(k_gemm,  dim3(2048), dim3(256), 0, stream, y0, wih + (long)2 * NG * K0, xpb);
        hipLaunchKernelGGL(k_recur_solo, dim3(8), dim3(512), 0, stream, xpb, whh, bias, h0, c0, y0, d_out, 1, flag);
    }
    hipLaunchKernelGGL(k_maxpool, dim3(256),  dim3(256), 0, stream, d_out, d_out, flag);
}